// Round 1
// baseline (63.249 us; speedup 1.0000x reference)
//
#include <hip/hip_runtime.h>
#include <math.h>

// Problem constants (match reference)
#define BN 32
#define RR 13
#define CC 13
#define AA 5
#define KK 20
#define CELLSZ 25            // K + 5
#define NN (RR * CC * AA)    // 845
#define THRESH 0.5f
#define NMS_TH 0.4f

#define BLOCK 1024
#define NWAVE (BLOCK / 64)   // 16 waves
// At most one class per cell can exceed THRESH=0.5 (softmax sums to 1, obj<1),
// so <= NN candidates per batch element. Pool lives entirely in LDS.
#define PCAP NN
#define PSTR 9               // record stride in floats (odd -> no LDS bank conflicts)
// record = { nk(int bits: k<<10|n), score, x1, y1, x2, y2, area, pad, pad }

__device__ __forceinline__ float sigmoidf_(float x) {
    return 1.0f / (1.0f + expf(-x));
}

// One block per batch element b. Phase 1: decode (one thread per cell),
// write box+obj+zeroed probs to out, append >THRESH candidates to LDS pool.
// Phase 2: one wave per class runs greedy NMS over the pool (wave-synchronous,
// tie-break score desc then n asc == reference's stable argsort order) and
// scatters kept scores into out. No workspace, no memset, one dispatch.
__global__ __launch_bounds__(BLOCK) void fused_kernel(
        const float* __restrict__ x,
        const float* __restrict__ bias,
        float* __restrict__ out) {
    __shared__ float pool[PCAP * PSTR];
    __shared__ int pcnt;

    const int b   = blockIdx.x;
    const int tid = threadIdx.x;
    if (tid == 0) pcnt = 0;
    __syncthreads();

    // ---------------- Phase 1: decode ----------------
    if (tid < NN) {
        const int n   = tid;
        const int r   = n / (CC * AA);
        const int rem = n % (CC * AA);
        const int c   = rem / AA;
        const int a   = rem % AA;

        const float* t = x + ((size_t)b * NN + n) * CELLSZ;

        float bx  = (sigmoidf_(t[0]) + (float)c) / (float)CC;
        float by  = (sigmoidf_(t[1]) + (float)r) / (float)RR;
        float bw  = expf(t[2]) * bias[2 * a]     / (float)RR;   // reference's R/C swap kept
        float bh  = expf(t[3]) * bias[2 * a + 1] / (float)CC;
        float obj = sigmoidf_(t[4]);

        float l[KK];
        float m = t[5];
#pragma unroll
        for (int k = 0; k < KK; ++k) { l[k] = t[5 + k]; m = fmaxf(m, l[k]); }
        float s = 0.0f;
#pragma unroll
        for (int k = 0; k < KK; ++k) { l[k] = expf(l[k] - m); s += l[k]; }

        float* o = out + ((size_t)b * NN + n) * CELLSZ;
        o[0] = bx; o[1] = by; o[2] = bw; o[3] = bh; o[4] = obj;
#pragma unroll
        for (int k = 0; k < KK; ++k) o[5 + k] = 0.0f;   // NMS phase fills kept ones

#pragma unroll
        for (int k = 0; k < KK; ++k) {
            float p = obj * (l[k] / s);   // same assoc as reference: obj * cls
            if (p > THRESH) {
                int slot = atomicAdd(&pcnt, 1);     // LDS atomic
                if (slot < PCAP) {                  // unreachable guard (see PCAP note)
                    float* rec = pool + slot * PSTR;
                    float x1 = bx - bw * 0.5f;
                    float y1 = by - bh * 0.5f;
                    rec[0] = __int_as_float((k << 10) | n);
                    rec[1] = p;
                    rec[2] = x1;
                    rec[3] = y1;
                    rec[4] = x1 + bw;
                    rec[5] = y1 + bh;
                    rec[6] = bw * bh;
                }
            }
        }
    }
    __syncthreads();   // pool complete; also orders the o[5+k]=0 global stores

    // ---------------- Phase 2: per-class NMS ----------------
    const int pc = min(pcnt, PCAP);
    if (pc == 0) return;                 // block-uniform
    const int wave = tid >> 6;
    const int lane = tid & 63;
    const int T = (pc + 63) >> 6;        // slots per lane (<= 14)

    for (int k = wave; k < KK; k += NWAVE) {
        // gather this class's candidates as a per-lane alive bitmask
        unsigned alive = 0;
        for (int tt = 0; tt < T; ++tt) {
            int j = lane + (tt << 6);
            if (j < pc) {
                int nk = __float_as_int(pool[j * PSTR]);
                if ((nk >> 10) == k) alive |= 1u << tt;
            }
        }
        if (__ballot(alive != 0) == 0ull) continue;   // wave-uniform: class empty

        while (true) {
            // local argmax (score desc, n asc)
            float bs = -1.0f;
            int   bn = 0x7fffffff;
            int   bg = -1;
            for (int tt = 0; tt < T; ++tt) {
                if ((alive >> tt) & 1u) {
                    int j = lane + (tt << 6);
                    float sc = pool[j * PSTR + 1];
                    int   nn = __float_as_int(pool[j * PSTR]) & 1023;
                    if (sc > bs || (sc == bs && nn < bn)) { bs = sc; bn = nn; bg = j; }
                }
            }
            // wave butterfly reduce
#pragma unroll
            for (int off = 32; off > 0; off >>= 1) {
                float os = __shfl_xor(bs, off);
                int   on = __shfl_xor(bn, off);
                int   og = __shfl_xor(bg, off);
                if (os > bs || (os == bs && on < bn)) { bs = os; bn = on; bg = og; }
            }
            if (bg < 0) break;           // wave-uniform: nothing alive

            // winner's box (LDS, broadcast-friendly)
            float X1 = pool[bg * PSTR + 2];
            float Y1 = pool[bg * PSTR + 3];
            float X2 = pool[bg * PSTR + 4];
            float Y2 = pool[bg * PSTR + 5];
            float AR = pool[bg * PSTR + 6];

            if ((bg & 63) == lane) {     // owner keeps it: write score, retire slot
                out[((size_t)b * NN + bn) * CELLSZ + 5 + k] = bs;
                alive &= ~(1u << (bg >> 6));
            }

            // suppress overlapping pending candidates of this class
            for (int tt = 0; tt < T; ++tt) {
                int j = lane + (tt << 6);
                if (((alive >> tt) & 1u) && j != bg) {
                    float iw = fmaxf(0.0f, fminf(X2, pool[j * PSTR + 4]) - fmaxf(X1, pool[j * PSTR + 2]));
                    float ih = fmaxf(0.0f, fminf(Y2, pool[j * PSTR + 5]) - fmaxf(Y1, pool[j * PSTR + 3]));
                    float inter = iw * ih;
                    float uni   = AR + pool[j * PSTR + 6] - inter;
                    float iou   = inter / fmaxf(uni, 1e-9f);
                    if (iou > NMS_TH) alive &= ~(1u << tt);
                }
            }
        }
    }
}

extern "C" void kernel_launch(void* const* d_in, const int* in_sizes, int n_in,
                              void* d_out, int out_size, void* d_ws, size_t ws_size,
                              hipStream_t stream) {
    const float* x    = (const float*)d_in[0];
    const float* bias = (const float*)d_in[1];
    // Single dispatch; workspace deliberately untouched (avoids the 256 MiB
    // per-iteration workspace re-poison fill that dominated the timed region).
    fused_kernel<<<BN, BLOCK, 0, stream>>>(x, bias, (float*)d_out);
}